// Round 3
// baseline (1517.945 us; speedup 1.0000x reference)
//
#include <hip/hip_runtime.h>
#include <cstdint>
#include <cstddef>

#define BN 4
#define NN 100000
#define CC 41
#define NCLS 40
#define NPROB (BN * NCLS)
#define PROP 100
#define NEGV (-1e9f)
#define IOU_T 0.3f
#define SCORE_T 0.7f
#define MAXR 4.135166556742356f
#define CAP 2048
#define TARGET 512
#define LISTCAP 32768
#define NBMPW 3125           // 100000/32
#define E07 0xBF333333u      // encf(0.7f)
#define ERHI 0xC1800000u     // encf(16.0f)
#define W0 ((unsigned long long)(ERHI - E07))

__device__ __forceinline__ unsigned int encf(float x) {
  unsigned int u = __float_as_uint(x);
  return (u & 0x80000000u) ? ~u : (u | 0x80000000u);
}
__device__ __forceinline__ float decf(unsigned int e) {
  unsigned int u = (e & 0x80000000u) ? (e ^ 0x80000000u) : ~e;
  return __uint_as_float(u);
}

__device__ __forceinline__ float iou_f(float ax1, float ay1, float ax2, float ay2,
                                       float bx1, float by1, float bx2, float by2) {
  float ix1 = fmaxf(ax1, bx1), iy1 = fmaxf(ay1, by1);
  float ix2 = fminf(ax2, bx2), iy2 = fminf(ay2, by2);
  float inter = fmaxf(ix2 - ix1, 0.0f) * fmaxf(iy2 - iy1, 0.0f);
  float a1 = (ax2 - ax1) * (ay2 - ay1);
  float a2 = (bx2 - bx1) * (by2 - by1);
  return inter / fmaxf(a1 + a2 - inter, 1e-9f);
}

// ---------------- Kernel A: decode + clip boxes, zero list counters ----------------
__global__ void decode_kernel(const float4* __restrict__ regress,
                              const float4* __restrict__ anchors,
                              float4* __restrict__ boxes,
                              unsigned int* __restrict__ gcnt) {
  int i = blockIdx.x * 256 + threadIdx.x;
  if (i < NPROB) gcnt[i] = 0u;
  if (i >= BN * NN) return;
  int n = i % NN;
  float4 d = regress[i];
  float4 a = anchors[n];
  float w = a.z - a.x, h = a.w - a.y;
  float cx = a.x + 0.5f * w, cy = a.y + 0.5f * h;
  float dx = d.x * 0.1f, dy = d.y * 0.1f;
  float dw = fminf(fmaxf(d.z * 0.2f, -MAXR), MAXR);
  float dh = fminf(fmaxf(d.w * 0.2f, -MAXR), MAXR);
  float pcx = cx + dx * w, pcy = cy + dy * h;
  float pw = w * expf(dw), ph = h * expf(dh);
  float4 o;
  o.x = fminf(fmaxf(pcx - 0.5f * pw, 0.0f), 1.0f);
  o.y = fminf(fmaxf(pcy - 0.5f * ph, 0.0f), 1.0f);
  o.z = fminf(fmaxf(pcx + 0.5f * pw, 0.0f), 1.0f);
  o.w = fminf(fmaxf(pcy + 0.5f * ph, 0.0f), 1.0f);
  boxes[i] = o;
}

// ---------------- Kernel B: fg + per-problem compact candidate lists ----------------
__global__ void score_kernel(const float* __restrict__ logits,
                             unsigned long long* __restrict__ glist,
                             unsigned int* __restrict__ gcnt,
                             unsigned int* __restrict__ fgb) {
  __shared__ float lg[256 * CC];  // 42 KB
  int b = blockIdx.y;
  int n0 = blockIdx.x * 256;
  int tid = threadIdx.x;
  int rows = NN - n0; if (rows > 256) rows = 256;
  int total4 = rows * CC / 4;
  const float4* src = (const float4*)(logits + ((size_t)b * NN + n0) * CC);
  float4* dst = (float4*)lg;
  for (int i = tid; i < total4; i += 256) dst[i] = src[i];
  __syncthreads();

  bool act = tid < rows;
  int n = n0 + tid;
  float bestv = 0.0f; int bestc = 0;
  if (act) {
    bestv = lg[tid * CC];
    #pragma unroll
    for (int c = 1; c < CC; ++c) {
      float v = lg[tid * CC + c];
      if (v > bestv) { bestv = v; bestc = c; }
    }
  }
  bool fg = act && (bestc > 0);
  int lane = tid & 63;
  int wbase = n0 + (tid & ~63);   // first n of this wave

  // fg bitmap (for rare dense fallback)
  unsigned long long mfg = __ballot(fg);
  if (lane == 0 && wbase < NN) fgb[b * NBMPW + (wbase >> 5)] = (unsigned int)mfg;
  if (lane == 32 && wbase + 32 < NN) fgb[b * NBMPW + (wbase >> 5) + 1] = (unsigned int)(mfg >> 32);

  // per-class eligible append (wave-aggregated atomics)
  for (int c = 1; c < CC; ++c) {
    float v = act ? lg[tid * CC + c] : 0.0f;
    bool elig = fg && (v >= SCORE_T);
    unsigned long long m = __ballot(elig);
    if (m == 0ull) continue;
    int prob = b * NCLS + (c - 1);
    if (elig) {
      int leader = __ffsll(m) - 1;
      unsigned int base = 0u;
      if (lane == leader) base = atomicAdd(&gcnt[prob], (unsigned int)__popcll(m));
      base = __shfl(base, leader);
      unsigned int pos = base + (unsigned int)__popcll(m & ((1ull << lane) - 1ull));
      if (pos < LISTCAP)
        glist[(size_t)prob * LISTCAP + pos] =
            ((unsigned long long)encf(v) << 32) | (unsigned int)n;
    }
  }
}

// ---------------- compact + sort + walk one window ----------------
__device__ int process_window(unsigned long long WLO, unsigned long long WUP, int idxbin,
                              bool dense, unsigned int cnt,
                              const unsigned long long* list, const float* lcol,
                              const unsigned int* fgp, const float4* bx4,
                              unsigned long long* keysL, float4* boxesL, float4* selL,
                              int* sh_cnt, int* sh_nsel,
                              int nsel, int prob, int* __restrict__ oidx,
                              float* __restrict__ osc, int tid) {
  __syncthreads();
  if (tid == 0) *sh_cnt = 0;
  __syncthreads();
  if (!dense) {
    for (unsigned int i = tid; i < cnt; i += 256) {
      unsigned long long k = list[i];
      unsigned long long E = k >> 32;
      unsigned int idx = (unsigned int)(k & 0xFFFFFFFFu);
      if (E >= WLO && E < WUP && (idxbin < 0 || (int)(idx >> 9) == idxbin)) {
        int slot = atomicAdd(sh_cnt, 1);
        if (slot < CAP) {
          keysL[slot] = (E << 32)
                      | ((unsigned long long)((131071u - idx) & 0x1FFFFu) << 15)
                      | (unsigned long long)slot;
          boxesL[slot] = bx4[idx];
        }
      }
    }
  } else {
    for (int i = tid; i < NN; i += 256) {
      if (!((fgp[i >> 5] >> (i & 31)) & 1u)) continue;
      float s = lcol[(size_t)i * CC];
      if (s < SCORE_T) continue;
      unsigned long long E = encf(s);
      if (E >= WLO && E < WUP && (idxbin < 0 || (i >> 9) == idxbin)) {
        int slot = atomicAdd(sh_cnt, 1);
        if (slot < CAP) {
          keysL[slot] = (E << 32)
                      | ((unsigned long long)((131071u - (unsigned int)i) & 0x1FFFFu) << 15)
                      | (unsigned long long)slot;
          boxesL[slot] = bx4[i];
        }
      }
    }
  }
  __syncthreads();
  int ncand = *sh_cnt; if (ncand > CAP) ncand = CAP;
  if (ncand == 0) return nsel;
  int M = 64; while (M < ncand) M <<= 1;
  for (int i = ncand + tid; i < M; i += 256) keysL[i] = 0ull;
  __syncthreads();
  for (int k = 2; k <= M; k <<= 1) {
    for (int j = k >> 1; j > 0; j >>= 1) {
      for (int t = tid; t < M; t += 256) {
        int ixj = t ^ j;
        if (ixj > t) {
          unsigned long long a = keysL[t], c2 = keysL[ixj];
          bool up = ((t & k) == 0);     // up-region: descending
          if (up ? (a < c2) : (a > c2)) { keysL[t] = c2; keysL[ixj] = a; }
        }
      }
      __syncthreads();
    }
  }
  if (tid < 64) {
    int lane = tid;
    int ns = nsel;
    for (int base = 0; base < ncand && ns < PROP; base += 64) {
      int i = base + lane;
      bool valid = i < ncand;
      unsigned long long key = valid ? keysL[i] : 0ull;
      int slot = (int)(key & 0x7FFF);
      float4 bx = boxesL[valid ? slot : 0];
      float sc = decf((unsigned int)(key >> 32));
      int aidx = 131071 - (int)((key >> 15) & 0x1FFFF);
      bool supp = false;
      for (int j = 0; j < ns; ++j) {
        float4 sb = selL[j];
        supp = supp || (iou_f(bx.x, bx.y, bx.z, bx.w, sb.x, sb.y, sb.z, sb.w) > IOU_T);
      }
      unsigned long long live = __ballot(valid && !supp);
      while (live && ns < PROP) {
        int kk = __ffsll(live) - 1;
        float x1 = __shfl(bx.x, kk), y1 = __shfl(bx.y, kk);
        float x2 = __shfl(bx.z, kk), y2 = __shfl(bx.w, kk);
        float ksc = __shfl(sc, kk);
        int kidx = __shfl(aidx, kk);
        if (lane == 0) {
          oidx[prob * PROP + ns] = kidx;
          osc [prob * PROP + ns] = ksc;
          selL[ns] = make_float4(x1, y1, x2, y2);
        }
        ns++;
        if (lane > kk && valid && !supp)
          supp = iou_f(bx.x, bx.y, bx.z, bx.w, x1, y1, x2, y2) > IOU_T;
        live = __ballot(valid && !supp) & ~((2ull << kk) - 1ull);
      }
    }
    if (lane == 0) *sh_nsel = ns;
  }
  __syncthreads();
  return *sh_nsel;
}

// ---------------- Kernel C: windowed sorted-walk greedy NMS ----------------
__launch_bounds__(256)
__global__ void nms_kernel(const unsigned long long* __restrict__ glist,
                           const unsigned int* __restrict__ gcnt,
                           const float* __restrict__ logits,
                           const unsigned int* __restrict__ fgb,
                           const float4* __restrict__ boxes,
                           int* __restrict__ oidx, float* __restrict__ osc) {
  __shared__ unsigned int hist[256];
  __shared__ unsigned long long keysL[CAP];   // 16 KB
  __shared__ float4 boxesL[CAP];              // 32 KB
  __shared__ float4 selL[PROP];
  __shared__ int sh_cnt, sh_nsel, sh_action, sh_bin;

  int prob = blockIdx.x;
  int b = prob / NCLS;
  int c1 = prob % NCLS + 1;
  int tid = threadIdx.x;

  unsigned int cnt = gcnt[prob];
  bool dense = cnt > LISTCAP;
  const unsigned long long* list = glist + (size_t)prob * LISTCAP;
  const float4* bx4 = boxes + (size_t)b * NN;
  const float* lcol = logits + (size_t)b * NN * CC + c1;
  const unsigned int* fgp = fgb + b * NBMPW;

  unsigned long long EHI = 1ull << 32;   // exclusive upper bound on unprocessed encoded scores
  int nsel = 0;

  for (int round = 0; round < 200 && nsel < PROP; ++round) {
    unsigned long long Rlo = E07, Rhi = ERHI;  // level-0: clamp map
    int level = 0;
    int action;
    unsigned long long WLO = 0, WUP = 0, E0 = 0;
    bool idxmode = false;

    while (true) {
      if (tid < 256) hist[tid] = 0u;
      __syncthreads();
      unsigned long long up = (level == 0) ? EHI : (Rhi < EHI ? Rhi : EHI);
      unsigned long long W = (level == 0) ? W0 : (Rhi - Rlo);
      if (!dense) {
        for (unsigned int i = tid; i < cnt; i += 256) {
          unsigned long long E = list[i] >> 32;
          if (E >= Rlo && E < up) {
            unsigned int bin = (level == 0 && E >= ERHI) ? 255u
                             : (unsigned int)(((E - Rlo) << 8) / W);
            atomicAdd(&hist[bin], 1u);
          }
        }
      } else {
        for (int i = tid; i < NN; i += 256) {
          if (!((fgp[i >> 5] >> (i & 31)) & 1u)) continue;
          float s = lcol[(size_t)i * CC];
          if (s < SCORE_T) continue;
          unsigned long long E = encf(s);
          if (E >= Rlo && E < up) {
            unsigned int bin = (level == 0 && E >= ERHI) ? 255u
                             : (unsigned int)(((E - Rlo) << 8) / W);
            atomicAdd(&hist[bin], 1u);
          }
        }
      }
      __syncthreads();
      if (tid == 0) {
        unsigned int cum = 0; int lo = 256; int act = 2; int rb = -1;
        for (int bb = 255; bb >= 0; --bb) {
          unsigned int nb = hist[bb];
          if (nb == 0u) continue;
          if (cum + nb > CAP) {
            if (cum == 0u) { act = 1; rb = bb; }
            break;
          }
          cum += nb; lo = bb; act = 0;
          if (cum >= TARGET) break;
        }
        sh_action = act; sh_bin = (act == 1) ? rb : lo;
      }
      __syncthreads();
      action = sh_action;
      int bsel = sh_bin;
      if (action == 2) break;
      if (action == 0) {
        WLO = Rlo + (((unsigned long long)bsel * W + 255ull) >> 8);
        WUP = up;
        break;
      }
      // refine bin bsel
      unsigned long long nRlo = Rlo + (((unsigned long long)bsel * W + 255ull) >> 8);
      unsigned long long nRhi = (level == 0 && bsel == 255)
                                ? EHI
                                : Rlo + (((unsigned long long)(bsel + 1) * W + 255ull) >> 8);
      if (nRhi > EHI) nRhi = EHI;
      Rlo = nRlo; Rhi = nRhi; level = 1;
      if (Rhi - Rlo <= 1ull) { idxmode = true; E0 = Rlo; break; }
    }

    if (action == 2) break;  // nothing remains

    if (!idxmode) {
      nsel = process_window(WLO, WUP, -1, dense, cnt, list, lcol, fgp, bx4,
                            keysL, boxesL, selL, &sh_cnt, &sh_nsel,
                            nsel, prob, oidx, osc, tid);
      EHI = WLO;
    } else {
      // degenerate: >CAP candidates share one float score; order = ascending idx
      for (int ib = 0; ib < 256 && nsel < PROP; ++ib)
        nsel = process_window(E0, E0 + 1ull, ib, dense, cnt, list, lcol, fgp, bx4,
                              keysL, boxesL, selL, &sh_cnt, &sh_nsel,
                              nsel, prob, oidx, osc, tid);
      EHI = E0;
    }
  }

  __syncthreads();
  for (int p = nsel + tid; p < PROP; p += 256) {
    oidx[prob * PROP + p] = -1;
    osc [prob * PROP + p] = NEGV;
  }
}

// ---------------- Kernel D: per-batch top-100 of 4000 (bitonic) + gather ----------------
__global__ void topk_kernel(const float* __restrict__ logits,
                            const float4* __restrict__ boxes,
                            const int* __restrict__ oidx,
                            const float* __restrict__ osc,
                            float* __restrict__ out) {
  __shared__ unsigned long long keys[4096];  // 32 KB
  int b = blockIdx.x;
  int tid = threadIdx.x;
  for (int i = tid; i < 4096; i += 256) {
    unsigned long long key = 0ull;
    if (i < NCLS * PROP) {
      float sc = osc[b * NCLS * PROP + i];
      key = ((unsigned long long)encf(sc) << 32) | (unsigned int)(~i);
    }
    keys[i] = ~key;  // ascending sort of ~key == descending by (score, lower i)
  }
  __syncthreads();
  for (int k = 2; k <= 4096; k <<= 1) {
    for (int j = k >> 1; j > 0; j >>= 1) {
      for (int t = tid; t < 4096; t += 256) {
        int ixj = t ^ j;
        if (ixj > t) {
          unsigned long long a = keys[t], c2 = keys[ixj];
          bool up = ((t & k) == 0);
          if ((a > c2) == up) { keys[t] = c2; keys[ixj] = a; }
        }
      }
      __syncthreads();
    }
  }
  if (tid < PROP) {
    unsigned long long key = ~keys[tid];
    unsigned int e = (unsigned int)(key >> 32);
    float sc = decf(e);
    bool ok = sc > 0.5f * NEGV;
    int kk = (int)(~(unsigned int)key);
    if (kk < 0 || kk >= NCLS * PROP) kk = 0;
    int idx = ok ? oidx[b * NCLS * PROP + kk] : 0;
    if (idx < 0) idx = 0;
    float m = ok ? 1.0f : 0.0f;
    const float* lp = logits + ((size_t)b * NN + idx) * CC;
    float* outl = out + ((size_t)b * PROP + tid) * CC;
    #pragma unroll
    for (int c = 0; c < CC; ++c) outl[c] = lp[c] * m;
    float4 bb = boxes[(size_t)b * NN + idx];
    float* outb = out + (size_t)BN * PROP * CC + ((size_t)b * PROP + tid) * 4;
    outb[0] = bb.x * m; outb[1] = bb.y * m; outb[2] = bb.z * m; outb[3] = bb.w * m;
  }
}

extern "C" void kernel_launch(void* const* d_in, const int* in_sizes, int n_in,
                              void* d_out, int out_size, void* d_ws, size_t ws_size,
                              hipStream_t stream) {
  const float* logits  = (const float*)d_in[0];  // (4,100000,41)
  const float* regress = (const float*)d_in[1];  // (4,100000,4)
  const float* anchors = (const float*)d_in[2];  // (100000,4)
  float* out = (float*)d_out;

  char* ws = (char*)d_ws;
  float4* boxes = (float4*)ws;                                   // 6,400,000 B
  unsigned long long* glist = (unsigned long long*)(ws + 6400000);          // 41,943,040 B
  unsigned int* gcnt = (unsigned int*)(ws + 6400000 + 41943040);            // 640 B
  unsigned int* fgb  = (unsigned int*)(ws + 6400000 + 41943040 + 640);      // 50,000 B
  float* osc = (float*)(ws + 6400000 + 41943040 + 640 + 50000);             // 64,000 B
  int*   oidx = (int*)(ws + 6400000 + 41943040 + 640 + 50000 + 64000);      // 64,000 B

  decode_kernel<<<(BN * NN + 255) / 256, 256, 0, stream>>>(
      (const float4*)regress, (const float4*)anchors, boxes, gcnt);
  score_kernel<<<dim3((NN + 255) / 256, BN), 256, 0, stream>>>(logits, glist, gcnt, fgb);
  nms_kernel<<<NPROB, 256, 0, stream>>>(glist, gcnt, logits, fgb, boxes, oidx, osc);
  topk_kernel<<<BN, 256, 0, stream>>>(logits, boxes, oidx, osc, out);
}

// Round 4
// 308.154 us; speedup vs baseline: 4.9259x; 4.9259x over previous
//
#include <hip/hip_runtime.h>
#include <cstdint>
#include <cstddef>

#define BN 4
#define NN 100000
#define CC 41
#define NCLS 40
#define NPROB (BN * NCLS)
#define PROP 100
#define NEGV (-1e9f)
#define IOU_T 0.3f
#define SCORE_T 0.7f
#define MAXR 4.135166556742356f
#define CAP 2048
#define TARGET 512
#define LISTCAP 32768
#define NBMPW 3125           // 100000/32
#define E07 0xBF333333u      // encf(0.7f)
#define ERHI 0xC1800000u     // encf(16.0f)
#define W0 ((unsigned long long)(ERHI - E07))

__device__ __forceinline__ unsigned int encf(float x) {
  unsigned int u = __float_as_uint(x);
  return (u & 0x80000000u) ? ~u : (u | 0x80000000u);
}
__device__ __forceinline__ float decf(unsigned int e) {
  unsigned int u = (e & 0x80000000u) ? (e ^ 0x80000000u) : ~e;
  return __uint_as_float(u);
}

__device__ __forceinline__ float iou_f(float ax1, float ay1, float ax2, float ay2,
                                       float bx1, float by1, float bx2, float by2) {
  float ix1 = fmaxf(ax1, bx1), iy1 = fmaxf(ay1, by1);
  float ix2 = fminf(ax2, bx2), iy2 = fminf(ay2, by2);
  float inter = fmaxf(ix2 - ix1, 0.0f) * fmaxf(iy2 - iy1, 0.0f);
  float a1 = (ax2 - ax1) * (ay2 - ay1);
  float a2 = (bx2 - bx1) * (by2 - by1);
  return inter / fmaxf(a1 + a2 - inter, 1e-9f);
}

// ---------------- Kernel A: decode + clip boxes, zero list counters ----------------
__global__ void decode_kernel(const float4* __restrict__ regress,
                              const float4* __restrict__ anchors,
                              float4* __restrict__ boxes,
                              unsigned int* __restrict__ gcnt) {
  int i = blockIdx.x * 256 + threadIdx.x;
  if (i < NPROB) gcnt[i] = 0u;
  if (i >= BN * NN) return;
  int n = i % NN;
  float4 d = regress[i];
  float4 a = anchors[n];
  float w = a.z - a.x, h = a.w - a.y;
  float cx = a.x + 0.5f * w, cy = a.y + 0.5f * h;
  float dx = d.x * 0.1f, dy = d.y * 0.1f;
  float dw = fminf(fmaxf(d.z * 0.2f, -MAXR), MAXR);
  float dh = fminf(fmaxf(d.w * 0.2f, -MAXR), MAXR);
  float pcx = cx + dx * w, pcy = cy + dy * h;
  float pw = w * expf(dw), ph = h * expf(dh);
  float4 o;
  o.x = fminf(fmaxf(pcx - 0.5f * pw, 0.0f), 1.0f);
  o.y = fminf(fmaxf(pcy - 0.5f * ph, 0.0f), 1.0f);
  o.z = fminf(fmaxf(pcx + 0.5f * pw, 0.0f), 1.0f);
  o.w = fminf(fmaxf(pcy + 0.5f * ph, 0.0f), 1.0f);
  boxes[i] = o;
}

// ---------------- Kernel B: fg + per-problem compact candidate lists ----------------
// One global atomic per (block, class), issued concurrently by wave 0.
__global__ void score_kernel(const float* __restrict__ logits,
                             unsigned long long* __restrict__ glist,
                             unsigned int* __restrict__ gcnt,
                             unsigned int* __restrict__ fgb) {
  __shared__ float lg[256 * CC];            // 42 KB
  __shared__ unsigned short wpre[NCLS][4];  // per-class per-wave exclusive prefix
  __shared__ unsigned int cbase[NCLS];      // per-class global base
  int b = blockIdx.y;
  int n0 = blockIdx.x * 256;
  int tid = threadIdx.x;
  int wave = tid >> 6, lane = tid & 63;
  int rows = NN - n0; if (rows > 256) rows = 256;
  int total4 = rows * CC / 4;
  const float4* src = (const float4*)(logits + ((size_t)b * NN + n0) * CC);
  float4* dst = (float4*)lg;
  for (int i = tid; i < total4; i += 256) dst[i] = src[i];
  __syncthreads();

  bool act = tid < rows;
  int n = n0 + tid;
  float bestv = 0.0f; int bestc = 0;
  if (act) {
    bestv = lg[tid * CC];
    #pragma unroll
    for (int c = 1; c < CC; ++c) {
      float v = lg[tid * CC + c];
      if (v > bestv) { bestv = v; bestc = c; }
    }
  }
  bool fg = act && (bestc > 0);
  int wbase = n0 + (tid & ~63);   // first n of this wave

  // fg bitmap (for rare dense fallback)
  unsigned long long mfg = __ballot(fg);
  if (lane == 0 && wbase < NN) fgb[b * NBMPW + (wbase >> 5)] = (unsigned int)mfg;
  if (lane == 32 && wbase + 32 < NN) fgb[b * NBMPW + (wbase >> 5) + 1] = (unsigned int)(mfg >> 32);

  // pass 1: per-wave per-class counts (no memory dependence -> pipelined)
  #pragma unroll 4
  for (int c = 1; c < CC; ++c) {
    float v = act ? lg[tid * CC + c] : 0.0f;
    unsigned long long m = __ballot(fg && (v >= SCORE_T));
    if (lane == 0) wpre[c - 1][wave] = (unsigned short)__popcll(m);
  }
  __syncthreads();

  // one atomic per class, all 40 issued concurrently from wave 0
  if (tid < NCLS) {
    unsigned int t0 = wpre[tid][0], t1 = wpre[tid][1], t2 = wpre[tid][2], t3 = wpre[tid][3];
    unsigned int tot = t0 + t1 + t2 + t3;
    unsigned int base = tot ? atomicAdd(&gcnt[b * NCLS + tid], tot) : 0u;
    cbase[tid] = base;
    wpre[tid][0] = 0;
    wpre[tid][1] = (unsigned short)t0;
    wpre[tid][2] = (unsigned short)(t0 + t1);
    wpre[tid][3] = (unsigned short)(t0 + t1 + t2);
  }
  __syncthreads();

  // pass 2: scatter (ballots identical to pass 1 -> positions deterministic)
  #pragma unroll 4
  for (int c = 1; c < CC; ++c) {
    float v = act ? lg[tid * CC + c] : 0.0f;
    bool elig = fg && (v >= SCORE_T);
    unsigned long long m = __ballot(elig);
    if (elig) {
      unsigned int pos = cbase[c - 1] + wpre[c - 1][wave]
                       + (unsigned int)__popcll(m & ((1ull << lane) - 1ull));
      if (pos < LISTCAP)
        glist[(size_t)(b * NCLS + (c - 1)) * LISTCAP + pos] =
            ((unsigned long long)encf(v) << 32) | (unsigned int)n;
    }
  }
}

// ---------------- compact + sort + walk one window ----------------
__device__ int process_window(unsigned long long WLO, unsigned long long WUP, int idxbin,
                              bool dense, unsigned int cnt,
                              const unsigned long long* list, const float* lcol,
                              const unsigned int* fgp, const float4* bx4,
                              unsigned long long* keysL, float4* boxesL, float4* selL,
                              int* sh_cnt, int* sh_nsel,
                              int nsel, int prob, int* __restrict__ oidx,
                              float* __restrict__ osc, int tid) {
  __syncthreads();
  if (tid == 0) *sh_cnt = 0;
  __syncthreads();
  if (!dense) {
    for (unsigned int i = tid; i < cnt; i += 256) {
      unsigned long long k = list[i];
      unsigned long long E = k >> 32;
      unsigned int idx = (unsigned int)(k & 0xFFFFFFFFu);
      if (E >= WLO && E < WUP && (idxbin < 0 || (int)(idx >> 9) == idxbin)) {
        int slot = atomicAdd(sh_cnt, 1);
        if (slot < CAP) {
          keysL[slot] = (E << 32)
                      | ((unsigned long long)((131071u - idx) & 0x1FFFFu) << 15)
                      | (unsigned long long)slot;
          boxesL[slot] = bx4[idx];
        }
      }
    }
  } else {
    for (int i = tid; i < NN; i += 256) {
      if (!((fgp[i >> 5] >> (i & 31)) & 1u)) continue;
      float s = lcol[(size_t)i * CC];
      if (s < SCORE_T) continue;
      unsigned long long E = encf(s);
      if (E >= WLO && E < WUP && (idxbin < 0 || (i >> 9) == idxbin)) {
        int slot = atomicAdd(sh_cnt, 1);
        if (slot < CAP) {
          keysL[slot] = (E << 32)
                      | ((unsigned long long)((131071u - (unsigned int)i) & 0x1FFFFu) << 15)
                      | (unsigned long long)slot;
          boxesL[slot] = bx4[i];
        }
      }
    }
  }
  __syncthreads();
  int ncand = *sh_cnt; if (ncand > CAP) ncand = CAP;
  if (ncand == 0) return nsel;
  int M = 64; while (M < ncand) M <<= 1;
  for (int i = ncand + tid; i < M; i += 256) keysL[i] = 0ull;
  __syncthreads();
  for (int k = 2; k <= M; k <<= 1) {
    for (int j = k >> 1; j > 0; j >>= 1) {
      for (int t = tid; t < M; t += 256) {
        int ixj = t ^ j;
        if (ixj > t) {
          unsigned long long a = keysL[t], c2 = keysL[ixj];
          bool up = ((t & k) == 0);     // up-region: descending
          if (up ? (a < c2) : (a > c2)) { keysL[t] = c2; keysL[ixj] = a; }
        }
      }
      __syncthreads();
    }
  }
  if (tid < 64) {
    int lane = tid;
    int ns = nsel;
    for (int base = 0; base < ncand && ns < PROP; base += 64) {
      int i = base + lane;
      bool valid = i < ncand;
      unsigned long long key = valid ? keysL[i] : 0ull;
      int slot = (int)(key & 0x7FFF);
      float4 bx = boxesL[valid ? slot : 0];
      float sc = decf((unsigned int)(key >> 32));
      int aidx = 131071 - (int)((key >> 15) & 0x1FFFF);
      bool supp = false;
      for (int j = 0; j < ns; ++j) {
        float4 sb = selL[j];
        supp = supp || (iou_f(bx.x, bx.y, bx.z, bx.w, sb.x, sb.y, sb.z, sb.w) > IOU_T);
      }
      unsigned long long live = __ballot(valid && !supp);
      while (live && ns < PROP) {
        int kk = __ffsll(live) - 1;
        float x1 = __shfl(bx.x, kk), y1 = __shfl(bx.y, kk);
        float x2 = __shfl(bx.z, kk), y2 = __shfl(bx.w, kk);
        float ksc = __shfl(sc, kk);
        int kidx = __shfl(aidx, kk);
        if (lane == 0) {
          oidx[prob * PROP + ns] = kidx;
          osc [prob * PROP + ns] = ksc;
          selL[ns] = make_float4(x1, y1, x2, y2);
        }
        ns++;
        if (lane > kk && valid && !supp)
          supp = iou_f(bx.x, bx.y, bx.z, bx.w, x1, y1, x2, y2) > IOU_T;
        live = __ballot(valid && !supp) & ~((2ull << kk) - 1ull);
      }
    }
    if (lane == 0) *sh_nsel = ns;
  }
  __syncthreads();
  return *sh_nsel;
}

// ---------------- Kernel C: windowed sorted-walk greedy NMS ----------------
__launch_bounds__(256)
__global__ void nms_kernel(const unsigned long long* __restrict__ glist,
                           const unsigned int* __restrict__ gcnt,
                           const float* __restrict__ logits,
                           const unsigned int* __restrict__ fgb,
                           const float4* __restrict__ boxes,
                           int* __restrict__ oidx, float* __restrict__ osc) {
  __shared__ unsigned int hist[256];
  __shared__ unsigned long long keysL[CAP];   // 16 KB
  __shared__ float4 boxesL[CAP];              // 32 KB
  __shared__ float4 selL[PROP];
  __shared__ int sh_cnt, sh_nsel, sh_action, sh_bin;

  int prob = blockIdx.x;
  int b = prob / NCLS;
  int c1 = prob % NCLS + 1;
  int tid = threadIdx.x;

  unsigned int cnt = gcnt[prob];
  bool dense = cnt > LISTCAP;
  const unsigned long long* list = glist + (size_t)prob * LISTCAP;
  const float4* bx4 = boxes + (size_t)b * NN;
  const float* lcol = logits + (size_t)b * NN * CC + c1;
  const unsigned int* fgp = fgb + b * NBMPW;

  unsigned long long EHI = 1ull << 32;   // exclusive upper bound on unprocessed encoded scores
  int nsel = 0;

  for (int round = 0; round < 200 && nsel < PROP; ++round) {
    unsigned long long Rlo = E07, Rhi = ERHI;  // level-0: clamp map
    int level = 0;
    int action;
    unsigned long long WLO = 0, WUP = 0, E0 = 0;
    bool idxmode = false;

    while (true) {
      if (tid < 256) hist[tid] = 0u;
      __syncthreads();
      unsigned long long up = (level == 0) ? EHI : (Rhi < EHI ? Rhi : EHI);
      unsigned long long W = (level == 0) ? W0 : (Rhi - Rlo);
      if (!dense) {
        for (unsigned int i = tid; i < cnt; i += 256) {
          unsigned long long E = list[i] >> 32;
          if (E >= Rlo && E < up) {
            unsigned int bin = (level == 0 && E >= ERHI) ? 255u
                             : (unsigned int)(((E - Rlo) << 8) / W);
            atomicAdd(&hist[bin], 1u);
          }
        }
      } else {
        for (int i = tid; i < NN; i += 256) {
          if (!((fgp[i >> 5] >> (i & 31)) & 1u)) continue;
          float s = lcol[(size_t)i * CC];
          if (s < SCORE_T) continue;
          unsigned long long E = encf(s);
          if (E >= Rlo && E < up) {
            unsigned int bin = (level == 0 && E >= ERHI) ? 255u
                             : (unsigned int)(((E - Rlo) << 8) / W);
            atomicAdd(&hist[bin], 1u);
          }
        }
      }
      __syncthreads();
      if (tid == 0) {
        unsigned int cum = 0; int lo = 256; int act = 2; int rb = -1;
        for (int bb = 255; bb >= 0; --bb) {
          unsigned int nb = hist[bb];
          if (nb == 0u) continue;
          if (cum + nb > CAP) {
            if (cum == 0u) { act = 1; rb = bb; }
            break;
          }
          cum += nb; lo = bb; act = 0;
          if (cum >= TARGET) break;
        }
        sh_action = act; sh_bin = (act == 1) ? rb : lo;
      }
      __syncthreads();
      action = sh_action;
      int bsel = sh_bin;
      if (action == 2) break;
      if (action == 0) {
        WLO = Rlo + (((unsigned long long)bsel * W + 255ull) >> 8);
        WUP = up;
        break;
      }
      // refine bin bsel
      unsigned long long nRlo = Rlo + (((unsigned long long)bsel * W + 255ull) >> 8);
      unsigned long long nRhi = (level == 0 && bsel == 255)
                                ? EHI
                                : Rlo + (((unsigned long long)(bsel + 1) * W + 255ull) >> 8);
      if (nRhi > EHI) nRhi = EHI;
      Rlo = nRlo; Rhi = nRhi; level = 1;
      if (Rhi - Rlo <= 1ull) { idxmode = true; E0 = Rlo; break; }
    }

    if (action == 2) break;  // nothing remains

    if (!idxmode) {
      nsel = process_window(WLO, WUP, -1, dense, cnt, list, lcol, fgp, bx4,
                            keysL, boxesL, selL, &sh_cnt, &sh_nsel,
                            nsel, prob, oidx, osc, tid);
      EHI = WLO;
    } else {
      // degenerate: >CAP candidates share one float score; order = ascending idx
      for (int ib = 0; ib < 256 && nsel < PROP; ++ib)
        nsel = process_window(E0, E0 + 1ull, ib, dense, cnt, list, lcol, fgp, bx4,
                              keysL, boxesL, selL, &sh_cnt, &sh_nsel,
                              nsel, prob, oidx, osc, tid);
      EHI = E0;
    }
  }

  __syncthreads();
  for (int p = nsel + tid; p < PROP; p += 256) {
    oidx[prob * PROP + p] = -1;
    osc [prob * PROP + p] = NEGV;
  }
}

// ---------------- Kernel D: per-batch top-100 of 4000 (bitonic, 1024 thr) + gather ----------------
__global__ void topk_kernel(const float* __restrict__ logits,
                            const float4* __restrict__ boxes,
                            const int* __restrict__ oidx,
                            const float* __restrict__ osc,
                            float* __restrict__ out) {
  __shared__ unsigned long long keys[4096];  // 32 KB
  int b = blockIdx.x;
  int tid = threadIdx.x;
  for (int i = tid; i < 4096; i += 1024) {
    unsigned long long key = 0ull;
    if (i < NCLS * PROP) {
      float sc = osc[b * NCLS * PROP + i];
      key = ((unsigned long long)encf(sc) << 32) | (unsigned int)(~i);
    }
    keys[i] = ~key;  // ascending sort of ~key == descending by (score, lower i)
  }
  __syncthreads();
  for (int k = 2; k <= 4096; k <<= 1) {
    for (int j = k >> 1; j > 0; j >>= 1) {
      for (int t = tid; t < 4096; t += 1024) {
        int ixj = t ^ j;
        if (ixj > t) {
          unsigned long long a = keys[t], c2 = keys[ixj];
          bool up = ((t & k) == 0);
          if ((a > c2) == up) { keys[t] = c2; keys[ixj] = a; }
        }
      }
      __syncthreads();
    }
  }
  if (tid < PROP) {
    unsigned long long key = ~keys[tid];
    unsigned int e = (unsigned int)(key >> 32);
    float sc = decf(e);
    bool ok = sc > 0.5f * NEGV;
    int kk = (int)(~(unsigned int)key);
    if (kk < 0 || kk >= NCLS * PROP) kk = 0;
    int idx = ok ? oidx[b * NCLS * PROP + kk] : 0;
    if (idx < 0) idx = 0;
    float m = ok ? 1.0f : 0.0f;
    const float* lp = logits + ((size_t)b * NN + idx) * CC;
    float* outl = out + ((size_t)b * PROP + tid) * CC;
    #pragma unroll
    for (int c = 0; c < CC; ++c) outl[c] = lp[c] * m;
    float4 bb = boxes[(size_t)b * NN + idx];
    float* outb = out + (size_t)BN * PROP * CC + ((size_t)b * PROP + tid) * 4;
    outb[0] = bb.x * m; outb[1] = bb.y * m; outb[2] = bb.z * m; outb[3] = bb.w * m;
  }
}

extern "C" void kernel_launch(void* const* d_in, const int* in_sizes, int n_in,
                              void* d_out, int out_size, void* d_ws, size_t ws_size,
                              hipStream_t stream) {
  const float* logits  = (const float*)d_in[0];  // (4,100000,41)
  const float* regress = (const float*)d_in[1];  // (4,100000,4)
  const float* anchors = (const float*)d_in[2];  // (100000,4)
  float* out = (float*)d_out;

  char* ws = (char*)d_ws;
  float4* boxes = (float4*)ws;                                              // 6,400,000 B
  unsigned long long* glist = (unsigned long long*)(ws + 6400000);          // 41,943,040 B
  unsigned int* gcnt = (unsigned int*)(ws + 6400000 + 41943040);            // 640 B
  unsigned int* fgb  = (unsigned int*)(ws + 6400000 + 41943040 + 640);      // 50,000 B
  float* osc = (float*)(ws + 6400000 + 41943040 + 640 + 50000);             // 64,000 B
  int*   oidx = (int*)(ws + 6400000 + 41943040 + 640 + 50000 + 64000);      // 64,000 B

  decode_kernel<<<(BN * NN + 255) / 256, 256, 0, stream>>>(
      (const float4*)regress, (const float4*)anchors, boxes, gcnt);
  score_kernel<<<dim3((NN + 255) / 256, BN), 256, 0, stream>>>(logits, glist, gcnt, fgb);
  nms_kernel<<<NPROB, 256, 0, stream>>>(glist, gcnt, logits, fgb, boxes, oidx, osc);
  topk_kernel<<<BN, 1024, 0, stream>>>(logits, boxes, oidx, osc, out);
}

// Round 5
// 296.031 us; speedup vs baseline: 5.1276x; 1.0410x over previous
//
#include <hip/hip_runtime.h>
#include <cstdint>
#include <cstddef>

#define BN 4
#define NN 100000
#define CC 41
#define NCLS 40
#define NPROB (BN * NCLS)
#define PROP 100
#define NEGV (-1e9f)
#define IOU_T 0.3f
#define SCORE_T 0.7f
#define MAXR 4.135166556742356f
#define CAP 2048
#define TARGET 512
#define LISTCAP 26624
#define NBMPW 3125           // 100000/32
#define E07 0xBF333333u      // encf(0.7f)
#define ERHI 0xC1800000u     // encf(16.0f)
#define W0 ((unsigned long long)(ERHI - E07))
#define NT3 1024             // threads in nms_finish
#define CHK 8192             // list elements per wide block (LISTCAP/CHK < 4 chunks... 26624/8192=3.25 -> 4)
#define NCHKB 4

__device__ __forceinline__ unsigned int encf(float x) {
  unsigned int u = __float_as_uint(x);
  return (u & 0x80000000u) ? ~u : (u | 0x80000000u);
}
__device__ __forceinline__ float decf(unsigned int e) {
  unsigned int u = (e & 0x80000000u) ? (e ^ 0x80000000u) : ~e;
  return __uint_as_float(u);
}

__device__ __forceinline__ float iou_f(float ax1, float ay1, float ax2, float ay2,
                                       float bx1, float by1, float bx2, float by2) {
  float ix1 = fmaxf(ax1, bx1), iy1 = fmaxf(ay1, by1);
  float ix2 = fminf(ax2, bx2), iy2 = fminf(ay2, by2);
  float inter = fmaxf(ix2 - ix1, 0.0f) * fmaxf(iy2 - iy1, 0.0f);
  float a1 = (ax2 - ax1) * (ay2 - ay1);
  float a2 = (bx2 - bx1) * (by2 - by1);
  return inter / fmaxf(a1 + a2 - inter, 1e-9f);
}

// selection from a 256-bin level-0 histogram; returns action (0=window,1=refine,2=empty)
// and the window low bin in *lo_out. Must be identical everywhere it is used.
__device__ __forceinline__ int select_window(const unsigned int* h, int* lo_out) {
  unsigned int cum = 0; int lo = 256; int act = 2;
  for (int bb = 255; bb >= 0; --bb) {
    unsigned int nb = h[bb];
    if (nb == 0u) continue;
    if (cum + nb > CAP) {
      if (cum == 0u) { act = 1; }
      break;
    }
    cum += nb; lo = bb; act = 0;
    if (cum >= TARGET) break;
  }
  *lo_out = lo;
  return act;
}

// ---------------- Kernel A: decode + clip boxes, zero counters ----------------
__global__ void decode_kernel(const float4* __restrict__ regress,
                              const float4* __restrict__ anchors,
                              float4* __restrict__ boxes,
                              unsigned int* __restrict__ gcnt,
                              unsigned int* __restrict__ ghist,
                              unsigned int* __restrict__ wcnt) {
  int i = blockIdx.x * 256 + threadIdx.x;
  if (i < NPROB) { gcnt[i] = 0u; wcnt[i] = 0u; }
  if (i < NPROB * 256) ghist[i] = 0u;
  if (i >= BN * NN) return;
  int n = i % NN;
  float4 d = regress[i];
  float4 a = anchors[n];
  float w = a.z - a.x, h = a.w - a.y;
  float cx = a.x + 0.5f * w, cy = a.y + 0.5f * h;
  float dx = d.x * 0.1f, dy = d.y * 0.1f;
  float dw = fminf(fmaxf(d.z * 0.2f, -MAXR), MAXR);
  float dh = fminf(fmaxf(d.w * 0.2f, -MAXR), MAXR);
  float pcx = cx + dx * w, pcy = cy + dy * h;
  float pw = w * expf(dw), ph = h * expf(dh);
  float4 o;
  o.x = fminf(fmaxf(pcx - 0.5f * pw, 0.0f), 1.0f);
  o.y = fminf(fmaxf(pcy - 0.5f * ph, 0.0f), 1.0f);
  o.z = fminf(fmaxf(pcx + 0.5f * pw, 0.0f), 1.0f);
  o.w = fminf(fmaxf(pcy + 0.5f * ph, 0.0f), 1.0f);
  boxes[i] = o;
}

// ---------------- Kernel B: fg + per-problem compact candidate lists ----------------
__global__ void score_kernel(const float* __restrict__ logits,
                             unsigned long long* __restrict__ glist,
                             unsigned int* __restrict__ gcnt,
                             unsigned int* __restrict__ fgb) {
  __shared__ float lg[256 * CC];            // 42 KB
  __shared__ unsigned short wpre[NCLS][4];
  __shared__ unsigned int cbase[NCLS];
  int b = blockIdx.y;
  int n0 = blockIdx.x * 256;
  int tid = threadIdx.x;
  int wave = tid >> 6, lane = tid & 63;
  int rows = NN - n0; if (rows > 256) rows = 256;
  int total4 = rows * CC / 4;
  const float4* src = (const float4*)(logits + ((size_t)b * NN + n0) * CC);
  float4* dst = (float4*)lg;
  for (int i = tid; i < total4; i += 256) dst[i] = src[i];
  __syncthreads();

  bool act = tid < rows;
  int n = n0 + tid;
  float bestv = 0.0f; int bestc = 0;
  if (act) {
    bestv = lg[tid * CC];
    #pragma unroll
    for (int c = 1; c < CC; ++c) {
      float v = lg[tid * CC + c];
      if (v > bestv) { bestv = v; bestc = c; }
    }
  }
  bool fg = act && (bestc > 0);
  int wbase = n0 + (tid & ~63);

  unsigned long long mfg = __ballot(fg);
  if (lane == 0 && wbase < NN) fgb[b * NBMPW + (wbase >> 5)] = (unsigned int)mfg;
  if (lane == 32 && wbase + 32 < NN) fgb[b * NBMPW + (wbase >> 5) + 1] = (unsigned int)(mfg >> 32);

  #pragma unroll 4
  for (int c = 1; c < CC; ++c) {
    float v = act ? lg[tid * CC + c] : 0.0f;
    unsigned long long m = __ballot(fg && (v >= SCORE_T));
    if (lane == 0) wpre[c - 1][wave] = (unsigned short)__popcll(m);
  }
  __syncthreads();

  if (tid < NCLS) {
    unsigned int t0 = wpre[tid][0], t1 = wpre[tid][1], t2 = wpre[tid][2], t3 = wpre[tid][3];
    unsigned int tot = t0 + t1 + t2 + t3;
    unsigned int base = tot ? atomicAdd(&gcnt[b * NCLS + tid], tot) : 0u;
    cbase[tid] = base;
    wpre[tid][0] = 0;
    wpre[tid][1] = (unsigned short)t0;
    wpre[tid][2] = (unsigned short)(t0 + t1);
    wpre[tid][3] = (unsigned short)(t0 + t1 + t2);
  }
  __syncthreads();

  #pragma unroll 4
  for (int c = 1; c < CC; ++c) {
    float v = act ? lg[tid * CC + c] : 0.0f;
    bool elig = fg && (v >= SCORE_T);
    unsigned long long m = __ballot(elig);
    if (elig) {
      unsigned int pos = cbase[c - 1] + wpre[c - 1][wave]
                       + (unsigned int)__popcll(m & ((1ull << lane) - 1ull));
      if (pos < LISTCAP)
        glist[(size_t)(b * NCLS + (c - 1)) * LISTCAP + pos] =
            ((unsigned long long)encf(v) << 32) | (unsigned int)n;
    }
  }
}

// ---------------- Kernel C1: wide per-problem 256-bin histogram ----------------
__global__ void hist_kernel(const unsigned long long* __restrict__ glist,
                            const unsigned int* __restrict__ gcnt,
                            unsigned int* __restrict__ ghist) {
  __shared__ unsigned int h[256];
  int prob = blockIdx.y;
  int chunk = blockIdx.x;
  int tid = threadIdx.x;
  unsigned int cnt = gcnt[prob];
  if (cnt > LISTCAP) return;  // dense fallback handled in nms_finish
  h[tid] = 0u;
  __syncthreads();
  unsigned int lo = chunk * CHK;
  unsigned int hi = cnt < lo + CHK ? cnt : lo + CHK;
  const unsigned long long* list = glist + (size_t)prob * LISTCAP;
  for (unsigned int i = lo + tid; i < hi; i += 256) {
    unsigned long long E = list[i] >> 32;
    unsigned int bin = (E >= ERHI) ? 255u : (unsigned int)(((E - E07) << 8) / W0);
    atomicAdd(&h[bin], 1u);
  }
  __syncthreads();
  unsigned int v = h[tid];
  if (v) atomicAdd(&ghist[prob * 256 + tid], v);  // fire-and-forget
}

// ---------------- Kernel C2: wide window compaction ----------------
__global__ void compact_kernel(const unsigned long long* __restrict__ glist,
                               const unsigned int* __restrict__ gcnt,
                               const unsigned int* __restrict__ ghist,
                               unsigned long long* __restrict__ wbuf,
                               unsigned int* __restrict__ wcnt,
                               unsigned int* __restrict__ wflag,
                               unsigned int* __restrict__ gwlo) {
  __shared__ int sh_act;
  __shared__ unsigned int sh_wlo;
  int prob = blockIdx.y;
  int chunk = blockIdx.x;
  int tid = threadIdx.x;
  int lane = tid & 63;
  unsigned int cnt = gcnt[prob];
  if (tid == 0) {
    int act, lo;
    unsigned int wlo = 0;
    if (cnt > LISTCAP) act = 1;
    else {
      act = select_window(&ghist[prob * 256], &lo);
      if (act == 0) wlo = E07 + (unsigned int)(((unsigned long long)lo * W0 + 255ull) >> 8);
    }
    sh_act = act; sh_wlo = wlo;
    if (chunk == 0) { wflag[prob] = (act == 0) ? 0u : 1u; gwlo[prob] = wlo; }
  }
  __syncthreads();
  if (sh_act != 0) return;
  unsigned int wlo = sh_wlo;
  unsigned int lo = chunk * CHK;
  unsigned int hi = cnt < lo + CHK ? cnt : lo + CHK;
  const unsigned long long* list = glist + (size_t)prob * LISTCAP;
  for (unsigned int base = lo; base < hi; base += 256) {
    unsigned int i = base + tid;
    bool elig = false;
    unsigned long long k = 0, E = 0;
    unsigned int idx = 0;
    if (i < hi) {
      k = list[i];
      E = k >> 32;
      idx = (unsigned int)(k & 0xFFFFFFFFu);
      elig = (E >= (unsigned long long)wlo);
    }
    unsigned long long m = __ballot(elig);
    if (elig) {
      int leader = __ffsll(m) - 1;
      unsigned int wb = 0;
      if (lane == leader) wb = atomicAdd(&wcnt[prob], (unsigned int)__popcll(m));
      wb = __shfl(wb, leader);
      unsigned int pos = wb + (unsigned int)__popcll(m & ((1ull << lane) - 1ull));
      if (pos < CAP)
        wbuf[(size_t)prob * CAP + pos] =
            (E << 32) | ((unsigned long long)((131071u - idx) & 0x1FFFFu) << 15)
                      | (unsigned long long)pos;
    }
  }
}

// ---------------- sort + walk (shared) ----------------
__device__ int sort_walk(int ncand, int nsel,
                         unsigned long long* keysL, float4* boxesL, float4* selL,
                         int* sh_nsel, int prob, int* __restrict__ oidx,
                         float* __restrict__ osc, int tid) {
  if (ncand == 0) return nsel;
  int M = 64; while (M < ncand) M <<= 1;
  for (int i = ncand + tid; i < M; i += NT3) keysL[i] = 0ull;
  __syncthreads();
  for (int k = 2; k <= M; k <<= 1) {
    for (int j = k >> 1; j > 0; j >>= 1) {
      for (int t = tid; t < M; t += NT3) {
        int ixj = t ^ j;
        if (ixj > t) {
          unsigned long long a = keysL[t], c2 = keysL[ixj];
          bool up = ((t & k) == 0);     // up-region: descending
          if (up ? (a < c2) : (a > c2)) { keysL[t] = c2; keysL[ixj] = a; }
        }
      }
      __syncthreads();
    }
  }
  if (tid < 64) {
    int lane = tid;
    int ns = nsel;
    for (int base = 0; base < ncand && ns < PROP; base += 64) {
      int i = base + lane;
      bool valid = i < ncand;
      unsigned long long key = valid ? keysL[i] : 0ull;
      int slot = (int)(key & 0x7FFF);
      float4 bx = boxesL[valid ? slot : 0];
      float sc = decf((unsigned int)(key >> 32));
      int aidx = 131071 - (int)((key >> 15) & 0x1FFFF);
      bool supp = false;
      for (int j = 0; j < ns; ++j) {
        float4 sb = selL[j];
        supp = supp || (iou_f(bx.x, bx.y, bx.z, bx.w, sb.x, sb.y, sb.z, sb.w) > IOU_T);
      }
      unsigned long long live = __ballot(valid && !supp);
      while (live && ns < PROP) {
        int kk = __ffsll(live) - 1;
        float x1 = __shfl(bx.x, kk), y1 = __shfl(bx.y, kk);
        float x2 = __shfl(bx.z, kk), y2 = __shfl(bx.w, kk);
        float ksc = __shfl(sc, kk);
        int kidx = __shfl(aidx, kk);
        if (lane == 0) {
          oidx[prob * PROP + ns] = kidx;
          osc [prob * PROP + ns] = ksc;
          selL[ns] = make_float4(x1, y1, x2, y2);
        }
        ns++;
        if (lane > kk && valid && !supp)
          supp = iou_f(bx.x, bx.y, bx.z, bx.w, x1, y1, x2, y2) > IOU_T;
        live = __ballot(valid && !supp) & ~((2ull << kk) - 1ull);
      }
    }
    if (lane == 0) *sh_nsel = ns;
  }
  __syncthreads();
  return *sh_nsel;
}

// ---------------- compact + sort + walk one window (fallback path) ----------------
__device__ int process_window(unsigned long long WLO, unsigned long long WUP, int idxbin,
                              bool dense, unsigned int cnt,
                              const unsigned long long* list, const float* lcol,
                              const unsigned int* fgp, const float4* bx4,
                              unsigned long long* keysL, float4* boxesL, float4* selL,
                              int* sh_cnt, int* sh_nsel,
                              int nsel, int prob, int* __restrict__ oidx,
                              float* __restrict__ osc, int tid) {
  __syncthreads();
  if (tid == 0) *sh_cnt = 0;
  __syncthreads();
  if (!dense) {
    for (unsigned int i = tid; i < cnt; i += NT3) {
      unsigned long long k = list[i];
      unsigned long long E = k >> 32;
      unsigned int idx = (unsigned int)(k & 0xFFFFFFFFu);
      if (E >= WLO && E < WUP && (idxbin < 0 || (int)(idx >> 9) == idxbin)) {
        int slot = atomicAdd(sh_cnt, 1);
        if (slot < CAP) {
          keysL[slot] = (E << 32)
                      | ((unsigned long long)((131071u - idx) & 0x1FFFFu) << 15)
                      | (unsigned long long)slot;
          boxesL[slot] = bx4[idx];
        }
      }
    }
  } else {
    for (int i = tid; i < NN; i += NT3) {
      if (!((fgp[i >> 5] >> (i & 31)) & 1u)) continue;
      float s = lcol[(size_t)i * CC];
      if (s < SCORE_T) continue;
      unsigned long long E = encf(s);
      if (E >= WLO && E < WUP && (idxbin < 0 || (i >> 9) == idxbin)) {
        int slot = atomicAdd(sh_cnt, 1);
        if (slot < CAP) {
          keysL[slot] = (E << 32)
                      | ((unsigned long long)((131071u - (unsigned int)i) & 0x1FFFFu) << 15)
                      | (unsigned long long)slot;
          boxesL[slot] = bx4[i];
        }
      }
    }
  }
  __syncthreads();
  int ncand = *sh_cnt; if (ncand > CAP) ncand = CAP;
  return sort_walk(ncand, nsel, keysL, boxesL, selL, sh_nsel, prob, oidx, osc, tid);
}

// ---------------- Kernel C3: per-problem sort+walk (+exact fallback) ----------------
__launch_bounds__(NT3)
__global__ void nms_finish(const unsigned long long* __restrict__ glist,
                           const unsigned int* __restrict__ gcnt,
                           const float* __restrict__ logits,
                           const unsigned int* __restrict__ fgb,
                           const float4* __restrict__ boxes,
                           const unsigned int* __restrict__ ghist,
                           const unsigned long long* __restrict__ wbuf,
                           const unsigned int* __restrict__ wcnt,
                           const unsigned int* __restrict__ wflag,
                           const unsigned int* __restrict__ gwlo,
                           int* __restrict__ oidx, float* __restrict__ osc) {
  __shared__ unsigned int hist[256];
  __shared__ unsigned long long keysL[CAP];   // 16 KB
  __shared__ float4 boxesL[CAP];              // 32 KB
  __shared__ float4 selL[PROP];
  __shared__ int sh_cnt, sh_nsel, sh_action, sh_bin;

  int prob = blockIdx.x;
  int b = prob / NCLS;
  int c1 = prob % NCLS + 1;
  int tid = threadIdx.x;

  unsigned int cnt = gcnt[prob];
  bool dense = cnt > LISTCAP;
  const unsigned long long* list = glist + (size_t)prob * LISTCAP;
  const float4* bx4 = boxes + (size_t)b * NN;
  const float* lcol = logits + (size_t)b * NN * CC + c1;
  const unsigned int* fgp = fgb + b * NBMPW;

  unsigned long long EHI = 1ull << 32;
  int nsel = 0;

  // fast path: precompacted window
  if (wflag[prob] == 0u) {
    int ncand = (int)wcnt[prob]; if (ncand > CAP) ncand = CAP;
    for (int i = tid; i < ncand; i += NT3) {
      unsigned long long k = wbuf[(size_t)prob * CAP + i];
      keysL[i] = k;
      unsigned int idx = 131071u - (unsigned int)((k >> 15) & 0x1FFFFu);
      boxesL[i] = bx4[idx];
    }
    __syncthreads();
    nsel = sort_walk(ncand, 0, keysL, boxesL, selL, &sh_nsel, prob, oidx, osc, tid);
    EHI = gwlo[prob];
  }

  // exact fallback rounds
  for (int round = 0; round < 200 && nsel < PROP; ++round) {
    unsigned long long Rlo = E07, Rhi = ERHI;
    int level = 0;
    int action;
    unsigned long long WLO = 0, WUP = 0, E0 = 0;
    bool idxmode = false;

    while (true) {
      if (tid < 256) hist[tid] = 0u;
      __syncthreads();
      unsigned long long up = (level == 0) ? EHI : (Rhi < EHI ? Rhi : EHI);
      unsigned long long W = (level == 0) ? W0 : (Rhi - Rlo);
      if (!dense) {
        for (unsigned int i = tid; i < cnt; i += NT3) {
          unsigned long long E = list[i] >> 32;
          if (E >= Rlo && E < up) {
            unsigned int bin = (level == 0 && E >= ERHI) ? 255u
                             : (unsigned int)(((E - Rlo) << 8) / W);
            atomicAdd(&hist[bin], 1u);
          }
        }
      } else {
        for (int i = tid; i < NN; i += NT3) {
          if (!((fgp[i >> 5] >> (i & 31)) & 1u)) continue;
          float s = lcol[(size_t)i * CC];
          if (s < SCORE_T) continue;
          unsigned long long E = encf(s);
          if (E >= Rlo && E < up) {
            unsigned int bin = (level == 0 && E >= ERHI) ? 255u
                             : (unsigned int)(((E - Rlo) << 8) / W);
            atomicAdd(&hist[bin], 1u);
          }
        }
      }
      __syncthreads();
      if (tid == 0) {
        int lo;
        int act = select_window(hist, &lo);
        int rb = -1;
        if (act == 1) {
          // find the top nonzero bin (the oversized one)
          for (int bb = 255; bb >= 0; --bb) if (hist[bb]) { rb = bb; break; }
        }
        sh_action = act; sh_bin = (act == 1) ? rb : lo;
      }
      __syncthreads();
      action = sh_action;
      int bsel = sh_bin;
      if (action == 2) break;
      if (action == 0) {
        WLO = Rlo + (((unsigned long long)bsel * W + 255ull) >> 8);
        WUP = up;
        break;
      }
      unsigned long long nRlo = Rlo + (((unsigned long long)bsel * W + 255ull) >> 8);
      unsigned long long nRhi = (level == 0 && bsel == 255)
                                ? EHI
                                : Rlo + (((unsigned long long)(bsel + 1) * W + 255ull) >> 8);
      if (nRhi > EHI) nRhi = EHI;
      Rlo = nRlo; Rhi = nRhi; level = 1;
      if (Rhi - Rlo <= 1ull) { idxmode = true; E0 = Rlo; break; }
    }

    if (action == 2) break;

    if (!idxmode) {
      nsel = process_window(WLO, WUP, -1, dense, cnt, list, lcol, fgp, bx4,
                            keysL, boxesL, selL, &sh_cnt, &sh_nsel,
                            nsel, prob, oidx, osc, tid);
      EHI = WLO;
    } else {
      for (int ib = 0; ib < 256 && nsel < PROP; ++ib)
        nsel = process_window(E0, E0 + 1ull, ib, dense, cnt, list, lcol, fgp, bx4,
                              keysL, boxesL, selL, &sh_cnt, &sh_nsel,
                              nsel, prob, oidx, osc, tid);
      EHI = E0;
    }
  }

  __syncthreads();
  for (int p = nsel + tid; p < PROP; p += NT3) {
    oidx[prob * PROP + p] = -1;
    osc [prob * PROP + p] = NEGV;
  }
}

// ---------------- Kernel D: per-batch top-100 of 4000 (bitonic, 1024 thr) + gather ----------------
__global__ void topk_kernel(const float* __restrict__ logits,
                            const float4* __restrict__ boxes,
                            const int* __restrict__ oidx,
                            const float* __restrict__ osc,
                            float* __restrict__ out) {
  __shared__ unsigned long long keys[4096];  // 32 KB
  int b = blockIdx.x;
  int tid = threadIdx.x;
  for (int i = tid; i < 4096; i += 1024) {
    unsigned long long key = 0ull;
    if (i < NCLS * PROP) {
      float sc = osc[b * NCLS * PROP + i];
      key = ((unsigned long long)encf(sc) << 32) | (unsigned int)(~i);
    }
    keys[i] = ~key;
  }
  __syncthreads();
  for (int k = 2; k <= 4096; k <<= 1) {
    for (int j = k >> 1; j > 0; j >>= 1) {
      for (int t = tid; t < 4096; t += 1024) {
        int ixj = t ^ j;
        if (ixj > t) {
          unsigned long long a = keys[t], c2 = keys[ixj];
          bool up = ((t & k) == 0);
          if ((a > c2) == up) { keys[t] = c2; keys[ixj] = a; }
        }
      }
      __syncthreads();
    }
  }
  if (tid < PROP) {
    unsigned long long key = ~keys[tid];
    unsigned int e = (unsigned int)(key >> 32);
    float sc = decf(e);
    bool ok = sc > 0.5f * NEGV;
    int kk = (int)(~(unsigned int)key);
    if (kk < 0 || kk >= NCLS * PROP) kk = 0;
    int idx = ok ? oidx[b * NCLS * PROP + kk] : 0;
    if (idx < 0) idx = 0;
    float m = ok ? 1.0f : 0.0f;
    const float* lp = logits + ((size_t)b * NN + idx) * CC;
    float* outl = out + ((size_t)b * PROP + tid) * CC;
    #pragma unroll
    for (int c = 0; c < CC; ++c) outl[c] = lp[c] * m;
    float4 bb = boxes[(size_t)b * NN + idx];
    float* outb = out + (size_t)BN * PROP * CC + ((size_t)b * PROP + tid) * 4;
    outb[0] = bb.x * m; outb[1] = bb.y * m; outb[2] = bb.z * m; outb[3] = bb.w * m;
  }
}

extern "C" void kernel_launch(void* const* d_in, const int* in_sizes, int n_in,
                              void* d_out, int out_size, void* d_ws, size_t ws_size,
                              hipStream_t stream) {
  const float* logits  = (const float*)d_in[0];  // (4,100000,41)
  const float* regress = (const float*)d_in[1];  // (4,100000,4)
  const float* anchors = (const float*)d_in[2];  // (100000,4)
  float* out = (float*)d_out;

  char* ws = (char*)d_ws;
  size_t off = 0;
  float4* boxes = (float4*)(ws + off);            off += (size_t)BN * NN * 16;            // 6,400,000
  unsigned long long* glist = (unsigned long long*)(ws + off); off += (size_t)NPROB * LISTCAP * 8;  // 34,078,720
  unsigned int* gcnt = (unsigned int*)(ws + off); off += NPROB * 4;                        // 640
  unsigned int* fgb  = (unsigned int*)(ws + off); off += BN * NBMPW * 4;                   // 50,000
  float* osc = (float*)(ws + off);                off += NPROB * PROP * 4;                 // 64,000
  int*   oidx = (int*)(ws + off);                 off += NPROB * PROP * 4;                 // 64,000
  unsigned int* ghist = (unsigned int*)(ws + off); off += NPROB * 256 * 4;                 // 163,840
  unsigned long long* wbuf = (unsigned long long*)(ws + off); off += (size_t)NPROB * CAP * 8; // 2,621,440
  unsigned int* wcnt = (unsigned int*)(ws + off); off += NPROB * 4;
  unsigned int* wflag = (unsigned int*)(ws + off); off += NPROB * 4;
  unsigned int* gwlo = (unsigned int*)(ws + off);  off += NPROB * 4;

  decode_kernel<<<(BN * NN + 255) / 256, 256, 0, stream>>>(
      (const float4*)regress, (const float4*)anchors, boxes, gcnt, ghist, wcnt);
  score_kernel<<<dim3((NN + 255) / 256, BN), 256, 0, stream>>>(logits, glist, gcnt, fgb);
  hist_kernel<<<dim3(NCHKB, NPROB), 256, 0, stream>>>(glist, gcnt, ghist);
  compact_kernel<<<dim3(NCHKB, NPROB), 256, 0, stream>>>(glist, gcnt, ghist, wbuf, wcnt, wflag, gwlo);
  nms_finish<<<NPROB, NT3, 0, stream>>>(glist, gcnt, logits, fgb, boxes, ghist,
                                        wbuf, wcnt, wflag, gwlo, oidx, osc);
  topk_kernel<<<BN, 1024, 0, stream>>>(logits, boxes, oidx, osc, out);
}

// Round 6
// 218.168 us; speedup vs baseline: 6.9577x; 1.3569x over previous
//
#include <hip/hip_runtime.h>
#include <cstdint>
#include <cstddef>

#define BN 4
#define NN 100000
#define CC 41
#define NCLS 40
#define NPROB (BN * NCLS)
#define PROP 100
#define NEGV (-1e9f)
#define IOU_T 0.3f
#define SCORE_T 0.7f
#define MAXR 4.135166556742356f
#define CAP 2048
#define TARGET 512
#define LISTCAP 26624
#define NBMPW 3125           // 100000/32
#define E07 0xBF333333u      // encf(0.7f)
#define ERHI 0xC1800000u     // encf(16.0f)
#define W0 ((unsigned long long)(ERHI - E07))
#define NT3 1024             // threads in nms_finish
#define CHK 8192
#define NCHKB 4

__device__ __forceinline__ unsigned int encf(float x) {
  unsigned int u = __float_as_uint(x);
  return (u & 0x80000000u) ? ~u : (u | 0x80000000u);
}
__device__ __forceinline__ float decf(unsigned int e) {
  unsigned int u = (e & 0x80000000u) ? (e ^ 0x80000000u) : ~e;
  return __uint_as_float(u);
}

__device__ __forceinline__ float iou_f(float ax1, float ay1, float ax2, float ay2,
                                       float bx1, float by1, float bx2, float by2) {
  float ix1 = fmaxf(ax1, bx1), iy1 = fmaxf(ay1, by1);
  float ix2 = fminf(ax2, bx2), iy2 = fminf(ay2, by2);
  float inter = fmaxf(ix2 - ix1, 0.0f) * fmaxf(iy2 - iy1, 0.0f);
  float a1 = (ax2 - ax1) * (ay2 - ay1);
  float a2 = (bx2 - bx1) * (by2 - by1);
  return inter / fmaxf(a1 + a2 - inter, 1e-9f);
}

// selection from a 256-bin level-0 histogram; returns action (0=window,1=refine,2=empty)
__device__ __forceinline__ int select_window(const unsigned int* h, int* lo_out) {
  unsigned int cum = 0; int lo = 256; int act = 2;
  for (int bb = 255; bb >= 0; --bb) {
    unsigned int nb = h[bb];
    if (nb == 0u) continue;
    if (cum + nb > CAP) {
      if (cum == 0u) { act = 1; }
      break;
    }
    cum += nb; lo = bb; act = 0;
    if (cum >= TARGET) break;
  }
  *lo_out = lo;
  return act;
}

// ---------------- Kernel A: decode + clip boxes, zero counters ----------------
__global__ void decode_kernel(const float4* __restrict__ regress,
                              const float4* __restrict__ anchors,
                              float4* __restrict__ boxes,
                              unsigned int* __restrict__ gcnt,
                              unsigned int* __restrict__ ghist) {
  int i = blockIdx.x * 256 + threadIdx.x;
  if (i < NPROB) gcnt[i] = 0u;
  if (i < NPROB * 256) ghist[i] = 0u;
  if (i >= BN * NN) return;
  int n = i % NN;
  float4 d = regress[i];
  float4 a = anchors[n];
  float w = a.z - a.x, h = a.w - a.y;
  float cx = a.x + 0.5f * w, cy = a.y + 0.5f * h;
  float dx = d.x * 0.1f, dy = d.y * 0.1f;
  float dw = fminf(fmaxf(d.z * 0.2f, -MAXR), MAXR);
  float dh = fminf(fmaxf(d.w * 0.2f, -MAXR), MAXR);
  float pcx = cx + dx * w, pcy = cy + dy * h;
  float pw = w * expf(dw), ph = h * expf(dh);
  float4 o;
  o.x = fminf(fmaxf(pcx - 0.5f * pw, 0.0f), 1.0f);
  o.y = fminf(fmaxf(pcy - 0.5f * ph, 0.0f), 1.0f);
  o.z = fminf(fmaxf(pcx + 0.5f * pw, 0.0f), 1.0f);
  o.w = fminf(fmaxf(pcy + 0.5f * ph, 0.0f), 1.0f);
  boxes[i] = o;
}

// ---------------- Kernel B: fg + per-problem compact candidate lists ----------------
__global__ void score_kernel(const float* __restrict__ logits,
                             unsigned long long* __restrict__ glist,
                             unsigned int* __restrict__ gcnt,
                             unsigned int* __restrict__ fgb) {
  __shared__ float lg[256 * CC];            // 42 KB
  __shared__ unsigned short wpre[NCLS][4];
  __shared__ unsigned int cbase[NCLS];
  int b = blockIdx.y;
  int n0 = blockIdx.x * 256;
  int tid = threadIdx.x;
  int wave = tid >> 6, lane = tid & 63;
  int rows = NN - n0; if (rows > 256) rows = 256;
  int total4 = rows * CC / 4;
  const float4* src = (const float4*)(logits + ((size_t)b * NN + n0) * CC);
  float4* dst = (float4*)lg;
  for (int i = tid; i < total4; i += 256) dst[i] = src[i];
  __syncthreads();

  bool act = tid < rows;
  int n = n0 + tid;
  float bestv = 0.0f; int bestc = 0;
  if (act) {
    bestv = lg[tid * CC];
    #pragma unroll
    for (int c = 1; c < CC; ++c) {
      float v = lg[tid * CC + c];
      if (v > bestv) { bestv = v; bestc = c; }
    }
  }
  bool fg = act && (bestc > 0);
  int wbase = n0 + (tid & ~63);

  unsigned long long mfg = __ballot(fg);
  if (lane == 0 && wbase < NN) fgb[b * NBMPW + (wbase >> 5)] = (unsigned int)mfg;
  if (lane == 32 && wbase + 32 < NN) fgb[b * NBMPW + (wbase >> 5) + 1] = (unsigned int)(mfg >> 32);

  #pragma unroll 4
  for (int c = 1; c < CC; ++c) {
    float v = act ? lg[tid * CC + c] : 0.0f;
    unsigned long long m = __ballot(fg && (v >= SCORE_T));
    if (lane == 0) wpre[c - 1][wave] = (unsigned short)__popcll(m);
  }
  __syncthreads();

  if (tid < NCLS) {
    unsigned int t0 = wpre[tid][0], t1 = wpre[tid][1], t2 = wpre[tid][2], t3 = wpre[tid][3];
    unsigned int tot = t0 + t1 + t2 + t3;
    unsigned int base = tot ? atomicAdd(&gcnt[b * NCLS + tid], tot) : 0u;
    cbase[tid] = base;
    wpre[tid][0] = 0;
    wpre[tid][1] = (unsigned short)t0;
    wpre[tid][2] = (unsigned short)(t0 + t1);
    wpre[tid][3] = (unsigned short)(t0 + t1 + t2);
  }
  __syncthreads();

  #pragma unroll 4
  for (int c = 1; c < CC; ++c) {
    float v = act ? lg[tid * CC + c] : 0.0f;
    bool elig = fg && (v >= SCORE_T);
    unsigned long long m = __ballot(elig);
    if (elig) {
      unsigned int pos = cbase[c - 1] + wpre[c - 1][wave]
                       + (unsigned int)__popcll(m & ((1ull << lane) - 1ull));
      if (pos < LISTCAP)
        glist[(size_t)(b * NCLS + (c - 1)) * LISTCAP + pos] =
            ((unsigned long long)encf(v) << 32) | (unsigned int)n;
    }
  }
}

// ---------------- Kernel C1: wide per-problem 256-bin histogram ----------------
__global__ void hist_kernel(const unsigned long long* __restrict__ glist,
                            const unsigned int* __restrict__ gcnt,
                            unsigned int* __restrict__ ghist) {
  __shared__ unsigned int h[256];
  int prob = blockIdx.y;
  int chunk = blockIdx.x;
  int tid = threadIdx.x;
  unsigned int cnt = gcnt[prob];
  if (cnt > LISTCAP) return;  // dense fallback handled in nms_finish
  h[tid] = 0u;
  __syncthreads();
  unsigned int lo = chunk * CHK;
  unsigned int hi = cnt < lo + CHK ? cnt : lo + CHK;
  const unsigned long long* list = glist + (size_t)prob * LISTCAP;
  for (unsigned int i = lo + tid; i < hi; i += 256) {
    unsigned long long E = list[i] >> 32;
    unsigned int bin = (E >= ERHI) ? 255u : (unsigned int)(((E - E07) << 8) / W0);
    atomicAdd(&h[bin], 1u);
  }
  __syncthreads();
  unsigned int v = h[tid];
  if (v) atomicAdd(&ghist[prob * 256 + tid], v);  // fire-and-forget
}

// ---------------- sort + walk (shared) ----------------
__device__ int sort_walk(int ncand, int nsel,
                         unsigned long long* keysL, float4* boxesL, float4* selL,
                         int* sh_nsel, int prob, int* __restrict__ oidx,
                         float* __restrict__ osc, int tid) {
  if (ncand == 0) return nsel;
  int M = 64; while (M < ncand) M <<= 1;
  for (int i = ncand + tid; i < M; i += NT3) keysL[i] = 0ull;
  __syncthreads();
  for (int k = 2; k <= M; k <<= 1) {
    for (int j = k >> 1; j > 0; j >>= 1) {
      for (int t = tid; t < M; t += NT3) {
        int ixj = t ^ j;
        if (ixj > t) {
          unsigned long long a = keysL[t], c2 = keysL[ixj];
          bool up = ((t & k) == 0);     // up-region: descending
          if (up ? (a < c2) : (a > c2)) { keysL[t] = c2; keysL[ixj] = a; }
        }
      }
      __syncthreads();
    }
  }
  if (tid < 64) {
    int lane = tid;
    int ns = nsel;
    for (int base = 0; base < ncand && ns < PROP; base += 64) {
      int i = base + lane;
      bool valid = i < ncand;
      unsigned long long key = valid ? keysL[i] : 0ull;
      int slot = (int)(key & 0x7FFF);
      float4 bx = boxesL[valid ? slot : 0];
      float sc = decf((unsigned int)(key >> 32));
      int aidx = 131071 - (int)((key >> 15) & 0x1FFFF);
      bool supp = false;
      for (int j = 0; j < ns; ++j) {
        float4 sb = selL[j];
        supp = supp || (iou_f(bx.x, bx.y, bx.z, bx.w, sb.x, sb.y, sb.z, sb.w) > IOU_T);
      }
      unsigned long long live = __ballot(valid && !supp);
      while (live && ns < PROP) {
        int kk = __ffsll(live) - 1;
        float x1 = __shfl(bx.x, kk), y1 = __shfl(bx.y, kk);
        float x2 = __shfl(bx.z, kk), y2 = __shfl(bx.w, kk);
        float ksc = __shfl(sc, kk);
        int kidx = __shfl(aidx, kk);
        if (lane == 0) {
          oidx[prob * PROP + ns] = kidx;
          osc [prob * PROP + ns] = ksc;
          selL[ns] = make_float4(x1, y1, x2, y2);
        }
        ns++;
        if (lane > kk && valid && !supp)
          supp = iou_f(bx.x, bx.y, bx.z, bx.w, x1, y1, x2, y2) > IOU_T;
        live = __ballot(valid && !supp) & ~((2ull << kk) - 1ull);
      }
    }
    if (lane == 0) *sh_nsel = ns;
  }
  __syncthreads();
  return *sh_nsel;
}

// ---------------- compact + sort + walk one window (fallback path) ----------------
__device__ int process_window(unsigned long long WLO, unsigned long long WUP, int idxbin,
                              bool dense, unsigned int cnt,
                              const unsigned long long* list, const float* lcol,
                              const unsigned int* fgp, const float4* bx4,
                              unsigned long long* keysL, float4* boxesL, float4* selL,
                              int* sh_cnt, int* sh_nsel,
                              int nsel, int prob, int* __restrict__ oidx,
                              float* __restrict__ osc, int tid) {
  __syncthreads();
  if (tid == 0) *sh_cnt = 0;
  __syncthreads();
  if (!dense) {
    for (unsigned int i = tid; i < cnt; i += NT3) {
      unsigned long long k = list[i];
      unsigned long long E = k >> 32;
      unsigned int idx = (unsigned int)(k & 0xFFFFFFFFu);
      if (E >= WLO && E < WUP && (idxbin < 0 || (int)(idx >> 9) == idxbin)) {
        int slot = atomicAdd(sh_cnt, 1);
        if (slot < CAP) {
          keysL[slot] = (E << 32)
                      | ((unsigned long long)((131071u - idx) & 0x1FFFFu) << 15)
                      | (unsigned long long)slot;
          boxesL[slot] = bx4[idx];
        }
      }
    }
  } else {
    for (int i = tid; i < NN; i += NT3) {
      if (!((fgp[i >> 5] >> (i & 31)) & 1u)) continue;
      float s = lcol[(size_t)i * CC];
      if (s < SCORE_T) continue;
      unsigned long long E = encf(s);
      if (E >= WLO && E < WUP && (idxbin < 0 || (i >> 9) == idxbin)) {
        int slot = atomicAdd(sh_cnt, 1);
        if (slot < CAP) {
          keysL[slot] = (E << 32)
                      | ((unsigned long long)((131071u - (unsigned int)i) & 0x1FFFFu) << 15)
                      | (unsigned long long)slot;
          boxesL[slot] = bx4[i];
        }
      }
    }
  }
  __syncthreads();
  int ncand = *sh_cnt; if (ncand > CAP) ncand = CAP;
  return sort_walk(ncand, nsel, keysL, boxesL, selL, sh_nsel, prob, oidx, osc, tid);
}

// ---------------- Kernel C2: window compact (LDS atomics) + sort + walk ----------------
__launch_bounds__(NT3)
__global__ void nms_finish(const unsigned long long* __restrict__ glist,
                           const unsigned int* __restrict__ gcnt,
                           const float* __restrict__ logits,
                           const unsigned int* __restrict__ fgb,
                           const float4* __restrict__ boxes,
                           const unsigned int* __restrict__ ghist,
                           int* __restrict__ oidx, float* __restrict__ osc) {
  __shared__ unsigned int hist[256];
  __shared__ unsigned long long keysL[CAP];   // 16 KB
  __shared__ float4 boxesL[CAP];              // 32 KB
  __shared__ float4 selL[PROP];
  __shared__ int sh_cnt, sh_nsel, sh_action, sh_bin;
  __shared__ unsigned int sh_wlo;

  int prob = blockIdx.x;
  int b = prob / NCLS;
  int c1 = prob % NCLS + 1;
  int tid = threadIdx.x;

  unsigned int cnt = gcnt[prob];
  bool dense = cnt > LISTCAP;
  const unsigned long long* list = glist + (size_t)prob * LISTCAP;
  const float4* bx4 = boxes + (size_t)b * NN;
  const float* lcol = logits + (size_t)b * NN * CC + c1;
  const unsigned int* fgp = fgb + b * NBMPW;

  unsigned long long EHI = 1ull << 32;
  int nsel = 0;

  // fast path: compute window from precomputed histogram, compact via LDS atomic
  if (tid == 0) {
    int act = 1;
    unsigned int wlo = 0;
    if (!dense) {
      int lo;
      act = select_window(&ghist[prob * 256], &lo);
      if (act == 0) wlo = E07 + (unsigned int)(((unsigned long long)lo * W0 + 255ull) >> 8);
    }
    sh_action = act; sh_wlo = wlo; sh_cnt = 0;
  }
  __syncthreads();

  if (sh_action == 0) {
    unsigned long long wlo = sh_wlo;
    for (unsigned int i = tid; i < cnt; i += NT3) {
      unsigned long long k = list[i];
      unsigned long long E = k >> 32;
      if (E >= wlo) {
        unsigned int idx = (unsigned int)(k & 0xFFFFFFFFu);
        int slot = atomicAdd(&sh_cnt, 1);
        if (slot < CAP) {
          keysL[slot] = (E << 32)
                      | ((unsigned long long)((131071u - idx) & 0x1FFFFu) << 15)
                      | (unsigned long long)slot;
          boxesL[slot] = bx4[idx];
        }
      }
    }
    __syncthreads();
    int ncand = sh_cnt < CAP ? sh_cnt : CAP;
    nsel = sort_walk(ncand, 0, keysL, boxesL, selL, &sh_nsel, prob, oidx, osc, tid);
    EHI = sh_wlo;
  }

  // exact fallback rounds (rare: first window insufficient, dense, or degenerate)
  for (int round = 0; round < 200 && nsel < PROP; ++round) {
    unsigned long long Rlo = E07, Rhi = ERHI;
    int level = 0;
    int action;
    unsigned long long WLO = 0, WUP = 0, E0 = 0;
    bool idxmode = false;

    while (true) {
      if (tid < 256) hist[tid] = 0u;
      __syncthreads();
      unsigned long long up = (level == 0) ? EHI : (Rhi < EHI ? Rhi : EHI);
      unsigned long long W = (level == 0) ? W0 : (Rhi - Rlo);
      if (!dense) {
        for (unsigned int i = tid; i < cnt; i += NT3) {
          unsigned long long E = list[i] >> 32;
          if (E >= Rlo && E < up) {
            unsigned int bin = (level == 0 && E >= ERHI) ? 255u
                             : (unsigned int)(((E - Rlo) << 8) / W);
            atomicAdd(&hist[bin], 1u);
          }
        }
      } else {
        for (int i = tid; i < NN; i += NT3) {
          if (!((fgp[i >> 5] >> (i & 31)) & 1u)) continue;
          float s = lcol[(size_t)i * CC];
          if (s < SCORE_T) continue;
          unsigned long long E = encf(s);
          if (E >= Rlo && E < up) {
            unsigned int bin = (level == 0 && E >= ERHI) ? 255u
                             : (unsigned int)(((E - Rlo) << 8) / W);
            atomicAdd(&hist[bin], 1u);
          }
        }
      }
      __syncthreads();
      if (tid == 0) {
        int lo;
        int act = select_window(hist, &lo);
        int rb = -1;
        if (act == 1) {
          for (int bb = 255; bb >= 0; --bb) if (hist[bb]) { rb = bb; break; }
        }
        sh_action = act; sh_bin = (act == 1) ? rb : lo;
      }
      __syncthreads();
      action = sh_action;
      int bsel = sh_bin;
      if (action == 2) break;
      if (action == 0) {
        WLO = Rlo + (((unsigned long long)bsel * W + 255ull) >> 8);
        WUP = up;
        break;
      }
      unsigned long long nRlo = Rlo + (((unsigned long long)bsel * W + 255ull) >> 8);
      unsigned long long nRhi = (level == 0 && bsel == 255)
                                ? EHI
                                : Rlo + (((unsigned long long)(bsel + 1) * W + 255ull) >> 8);
      if (nRhi > EHI) nRhi = EHI;
      Rlo = nRlo; Rhi = nRhi; level = 1;
      if (Rhi - Rlo <= 1ull) { idxmode = true; E0 = Rlo; break; }
    }

    if (action == 2) break;

    if (!idxmode) {
      nsel = process_window(WLO, WUP, -1, dense, cnt, list, lcol, fgp, bx4,
                            keysL, boxesL, selL, &sh_cnt, &sh_nsel,
                            nsel, prob, oidx, osc, tid);
      EHI = WLO;
    } else {
      for (int ib = 0; ib < 256 && nsel < PROP; ++ib)
        nsel = process_window(E0, E0 + 1ull, ib, dense, cnt, list, lcol, fgp, bx4,
                              keysL, boxesL, selL, &sh_cnt, &sh_nsel,
                              nsel, prob, oidx, osc, tid);
      EHI = E0;
    }
  }

  __syncthreads();
  for (int p = nsel + tid; p < PROP; p += NT3) {
    oidx[prob * PROP + p] = -1;
    osc [prob * PROP + p] = NEGV;
  }
}

// ---------------- Kernel D: per-batch top-100 of 4000 (bitonic, 1024 thr) + gather ----------------
__global__ void topk_kernel(const float* __restrict__ logits,
                            const float4* __restrict__ boxes,
                            const int* __restrict__ oidx,
                            const float* __restrict__ osc,
                            float* __restrict__ out) {
  __shared__ unsigned long long keys[4096];  // 32 KB
  int b = blockIdx.x;
  int tid = threadIdx.x;
  for (int i = tid; i < 4096; i += 1024) {
    unsigned long long key = 0ull;
    if (i < NCLS * PROP) {
      float sc = osc[b * NCLS * PROP + i];
      key = ((unsigned long long)encf(sc) << 32) | (unsigned int)(~i);
    }
    keys[i] = ~key;
  }
  __syncthreads();
  for (int k = 2; k <= 4096; k <<= 1) {
    for (int j = k >> 1; j > 0; j >>= 1) {
      for (int t = tid; t < 4096; t += 1024) {
        int ixj = t ^ j;
        if (ixj > t) {
          unsigned long long a = keys[t], c2 = keys[ixj];
          bool up = ((t & k) == 0);
          if ((a > c2) == up) { keys[t] = c2; keys[ixj] = a; }
        }
      }
      __syncthreads();
    }
  }
  if (tid < PROP) {
    unsigned long long key = ~keys[tid];
    unsigned int e = (unsigned int)(key >> 32);
    float sc = decf(e);
    bool ok = sc > 0.5f * NEGV;
    int kk = (int)(~(unsigned int)key);
    if (kk < 0 || kk >= NCLS * PROP) kk = 0;
    int idx = ok ? oidx[b * NCLS * PROP + kk] : 0;
    if (idx < 0) idx = 0;
    float m = ok ? 1.0f : 0.0f;
    const float* lp = logits + ((size_t)b * NN + idx) * CC;
    float* outl = out + ((size_t)b * PROP + tid) * CC;
    #pragma unroll
    for (int c = 0; c < CC; ++c) outl[c] = lp[c] * m;
    float4 bb = boxes[(size_t)b * NN + idx];
    float* outb = out + (size_t)BN * PROP * CC + ((size_t)b * PROP + tid) * 4;
    outb[0] = bb.x * m; outb[1] = bb.y * m; outb[2] = bb.z * m; outb[3] = bb.w * m;
  }
}

extern "C" void kernel_launch(void* const* d_in, const int* in_sizes, int n_in,
                              void* d_out, int out_size, void* d_ws, size_t ws_size,
                              hipStream_t stream) {
  const float* logits  = (const float*)d_in[0];  // (4,100000,41)
  const float* regress = (const float*)d_in[1];  // (4,100000,4)
  const float* anchors = (const float*)d_in[2];  // (100000,4)
  float* out = (float*)d_out;

  char* ws = (char*)d_ws;
  size_t off = 0;
  float4* boxes = (float4*)(ws + off);            off += (size_t)BN * NN * 16;
  unsigned long long* glist = (unsigned long long*)(ws + off); off += (size_t)NPROB * LISTCAP * 8;
  unsigned int* gcnt = (unsigned int*)(ws + off); off += NPROB * 4;
  unsigned int* fgb  = (unsigned int*)(ws + off); off += BN * NBMPW * 4;
  float* osc = (float*)(ws + off);                off += NPROB * PROP * 4;
  int*   oidx = (int*)(ws + off);                 off += NPROB * PROP * 4;
  unsigned int* ghist = (unsigned int*)(ws + off); off += NPROB * 256 * 4;

  decode_kernel<<<(BN * NN + 255) / 256, 256, 0, stream>>>(
      (const float4*)regress, (const float4*)anchors, boxes, gcnt, ghist);
  score_kernel<<<dim3((NN + 255) / 256, BN), 256, 0, stream>>>(logits, glist, gcnt, fgb);
  hist_kernel<<<dim3(NCHKB, NPROB), 256, 0, stream>>>(glist, gcnt, ghist);
  nms_finish<<<NPROB, NT3, 0, stream>>>(glist, gcnt, logits, fgb, boxes, ghist, oidx, osc);
  topk_kernel<<<BN, 1024, 0, stream>>>(logits, boxes, oidx, osc, out);
}